// Round 2
// baseline (1866.769 us; speedup 1.0000x reference)
//
#include <hip/hip_runtime.h>
#include <math.h>

// ---------------------------------------------------------------------------
// WeaklySupervisedDetection
//   Phases 1-4 (conv/obj/topk/boxes): f32-bit-exact chains — DO NOT TOUCH the
//   arithmetic ORDER; they reproduce the np reference's ordering.
//   conv v3: x values are block-uniform -> direct global (scalarizable) loads,
//   no LDS; grid (625,2), 1 co/thread.
//   GEMMs: m97 structure + 2-phase LDS double-buffer (T3-minimum), kg-major
//   conflict-free LDS layout via permuted global_load_lds SOURCE (rule 21),
//   bijective XCD swizzle (T1, column-major linear id).
//   Softmaxes: fp64 math over fp32 logits (tiny kernels).
// ---------------------------------------------------------------------------

#define HN 50
#define WN 50
#define CN 512
#define AN 9
#define KTOP 2048
#define NCL 20
#define NOBJ 22500  // H*W*A

typedef unsigned short ushort_t;
typedef __attribute__((ext_vector_type(8))) short short8;
typedef __attribute__((ext_vector_type(4))) float floatx4;

__device__ float conv_zero_row[CN];  // .bss, zero-initialized at load

__device__ __forceinline__ ushort_t bf16_rne(float f) {
    unsigned int u = __float_as_uint(f);
    unsigned int r = (u + 0x7FFFu + ((u >> 16) & 1u)) >> 16;
    return (ushort_t)r;
}

__device__ __forceinline__ void gl_lds16(const void* g, void* l) {
    __builtin_amdgcn_global_load_lds(
        (const __attribute__((address_space(1))) unsigned int*)g,
        (__attribute__((address_space(3))) unsigned int*)l, 16, 0, 0);
}

// ---------------- conv 2x2 SAME, exact f32 tap chains ----------------------
// v3: grid (625, 2). Thread owns 1 co, 4 hw, 4 taps. x addresses are
// block-uniform -> global loads (scalar-cache friendly); zero-row for pad.
// Chain per output identical: c ascending, taps combined ((t0+t1)+t2)+t3+b.
__launch_bounds__(256)
__global__ void conv_chain_kernel(const float* __restrict__ feat,
                                  const float* __restrict__ rpnw,
                                  const float* __restrict__ rpnb,
                                  float* __restrict__ x32)
{
    const int tid = threadIdx.x;
    const int hwBase = blockIdx.x * 4;
    const int co = blockIdx.y * 256 + tid;

    const float* rp[4][4];
#pragma unroll
    for (int i = 0; i < 4; i++) {
        int hw = hwBase + i;
        int h = hw / WN, w = hw % WN;
#pragma unroll
        for (int t = 0; t < 4; t++) {
            int hy = h + (t >> 1), wx = w + (t & 1);
            rp[i][t] = (hy < HN && wx < WN)
                           ? feat + (size_t)(hy * WN + wx) * CN
                           : conv_zero_row;
        }
    }

    float acc[4][4];
#pragma unroll
    for (int i = 0; i < 4; i++)
#pragma unroll
        for (int t = 0; t < 4; t++) acc[i][t] = 0.f;

    for (int cq = 0; cq < CN; cq += 4) {
        float4 xv[4][4];
#pragma unroll
        for (int i = 0; i < 4; i++)
#pragma unroll
            for (int t = 0; t < 4; t++)
                xv[i][t] = *(const float4*)(rp[i][t] + cq);

#pragma unroll
        for (int cc = 0; cc < 4; cc++) {
            float wv[4];
#pragma unroll
            for (int t = 0; t < 4; t++)
                wv[t] = rpnw[(size_t)(t * CN + cq + cc) * CN + co];
#pragma unroll
            for (int i = 0; i < 4; i++)
#pragma unroll
                for (int t = 0; t < 4; t++) {
                    float xvv = cc == 0 ? xv[i][t].x
                              : cc == 1 ? xv[i][t].y
                              : cc == 2 ? xv[i][t].z : xv[i][t].w;
                    acc[i][t] = fmaf(xvv, wv[t], acc[i][t]);
                }
        }
    }

    float b = rpnb[co];
#pragma unroll
    for (int i = 0; i < 4; i++) {
        float v = ((acc[i][0] + acc[i][1]) + acc[i][2]) + acc[i][3];
        v = v + b;
        v = v > 0.f ? v : 0.f;
        x32[(size_t)(hwBase + i) * CN + co] = v;
    }
}

// ---------------- objectness: f32 chain -> f32 sigmoid key ------------------
__launch_bounds__(256)
__global__ void obj_chain_kernel(const float* __restrict__ x32,
                                 const float* __restrict__ clsw,
                                 const float* __restrict__ clsb,
                                 float* __restrict__ key)
{
    int i = blockIdx.x * 256 + threadIdx.x;
    if (i >= NOBJ) return;
    int hw = i / AN, a = i % AN;
    const float* xr = x32 + (size_t)hw * CN;
    float acc = 0.f;
    for (int c = 0; c < CN; c++) acc = fmaf(xr[c], clsw[c * AN + a], acc);
    float l32 = acc + clsb[a];
    float s32 = (float)(1.0 / (1.0 + exp(-(double)l32)));
    key[i] = s32;
}

// ---------------- exact top-K rank count on (f32 key desc, idx asc) --------
__launch_bounds__(256)
__global__ void topk_count_kernel(const float* __restrict__ key, int* __restrict__ cnt)
{
    __shared__ float ch[2048];
    int tid = threadIdx.x;
    int j0 = blockIdx.y * 2048;
    for (int t = tid; t < 2048; t += 256) {
        int jg = j0 + t;
        ch[t] = (jg < NOBJ) ? key[jg] : -1.0f;
    }
    int i = blockIdx.x * 256 + tid;
    float vi = (i < NOBJ) ? key[i] : 2.0f;
    __syncthreads();
    int c = 0;
    for (int t = 0; t < 2048; t++) {
        float vj = ch[t];
        int jg = j0 + t;
        c += (vj > vi || (vj == vi && jg < i)) ? 1 : 0;
    }
    if (i < NOBJ && c) atomicAdd(&cnt[i], c);
}

__launch_bounds__(256)
__global__ void topk_scatter_kernel(const int* __restrict__ cnt, int* __restrict__ sorted)
{
    int i = blockIdx.x * 256 + threadIdx.x;
    if (i < NOBJ) {
        int r = cnt[i];
        if (r < KTOP) sorted[r] = i;
    }
}

// ---------------- box regression (f32 chains) + transform (fp64) -----------
__launch_bounds__(256)
__global__ void boxes_kernel(const int* __restrict__ sorted,
                             const float* __restrict__ x32,
                             const float* __restrict__ regw,
                             const float* __restrict__ regb,
                             double* __restrict__ boxd,
                             float* __restrict__ outBoxes)
{
    int k = blockIdx.x * 256 + threadIdx.x;
    if (k >= KTOP) return;
    int i = sorted[k];
    int hw = i / AN, a = i % AN;
    const float* xr = x32 + (size_t)hw * CN;
    float r0 = 0.f, r1 = 0.f, r2 = 0.f, r3 = 0.f;
    for (int c = 0; c < CN; c++) {
        float xv = xr[c];
        const float* wr = regw + (size_t)c * (4 * AN) + 4 * a;
        r0 = fmaf(xv, wr[0], r0);
        r1 = fmaf(xv, wr[1], r1);
        r2 = fmaf(xv, wr[2], r2);
        r3 = fmaf(xv, wr[3], r3);
    }
    r0 = r0 + regb[4 * a + 0];
    r1 = r1 + regb[4 * a + 1];
    r2 = r2 + regb[4 * a + 2];
    r3 = r3 + regb[4 * a + 3];
    double s0 = 1.0 / (1.0 + exp(-(double)r0));
    double s1 = 1.0 / (1.0 + exp(-(double)r1));
    double s2 = 1.0 / (1.0 + exp(-(double)r2));
    double s3 = 1.0 / (1.0 + exp(-(double)r3));
    double x1 = s0 * (double)(WN - 2);
    double x2 = x1 + 1.0 + s1 * ((double)(WN - 1) - x1);
    double y1 = s2 * (double)(HN - 2);
    double y2 = y1 + 1.0 + s3 * ((double)(HN - 1) - y1);
    boxd[4 * k + 0] = x1; boxd[4 * k + 1] = x2;
    boxd[4 * k + 2] = y1; boxd[4 * k + 3] = y2;
    outBoxes[4 * k + 0] = (float)x1; outBoxes[4 * k + 1] = (float)x2;
    outBoxes[4 * k + 2] = (float)y1; outBoxes[4 * k + 3] = (float)y2;
}

// ---------------- ROI align -> pooled [K, 4608] (bf16) ---------------------
__launch_bounds__(256)
__global__ void roi_kernel(const float* __restrict__ feat,
                           const double* __restrict__ boxd,
                           ushort_t* __restrict__ pooled)
{
    int k = blockIdx.x;
    int tid = threadIdx.x;
    double x1 = boxd[4 * k + 0], x2 = boxd[4 * k + 1];
    double y1 = boxd[4 * k + 2], y2 = boxd[4 * k + 3];
    int ix0[3], ix1[3], iy0[3], iy1[3];
    double fx[3], fy[3];
#pragma unroll
    for (int p = 0; p < 3; p++) {
        double t = ((double)p + 0.5) / 3.0;
        double xsv = x1 + (x2 - x1) * t;
        double x0f = floor(xsv);
        fx[p] = xsv - x0f;
        int xi = (int)x0f;
        xi = xi < 0 ? 0 : (xi > WN - 1 ? WN - 1 : xi);
        ix0[p] = xi;
        ix1[p] = (xi + 1 > WN - 1) ? WN - 1 : xi + 1;
        double ysv = y1 + (y2 - y1) * t;
        double y0f = floor(ysv);
        fy[p] = ysv - y0f;
        int yi = (int)y0f;
        yi = yi < 0 ? 0 : (yi > HN - 1 ? HN - 1 : yi);
        iy0[p] = yi;
        iy1[p] = (yi + 1 > HN - 1) ? HN - 1 : yi + 1;
    }
#pragma unroll
    for (int pp = 0; pp < 9; pp++) {
        int py = pp / 3, px = pp % 3;
        double w00 = (1.0 - fy[py]) * (1.0 - fx[px]);
        double w01 = (1.0 - fy[py]) * fx[px];
        double w10 = fy[py] * (1.0 - fx[px]);
        double w11 = fy[py] * fx[px];
        const float* f00 = feat + (size_t)(iy0[py] * WN + ix0[px]) * CN;
        const float* f01 = feat + (size_t)(iy0[py] * WN + ix1[px]) * CN;
        const float* f10 = feat + (size_t)(iy1[py] * WN + ix0[px]) * CN;
        const float* f11 = feat + (size_t)(iy1[py] * WN + ix1[px]) * CN;
        ushort_t* dst = pooled + ((size_t)k * 9 + pp) * CN;
        for (int c = tid; c < CN; c += 256) {
            double v = w00 * (double)f00[c] + w01 * (double)f01[c]
                     + w10 * (double)f10[c] + w11 * (double)f11[c];
            dst[c] = bf16_rne((float)v);
        }
    }
}

// ---------------- transpose + cvt: W fp32 [K,N] cols [n0,n0+Nsub) ----------
//                  -> Wt bf16 [Nsub][K]
__launch_bounds__(256)
__global__ void transpose_cvt_kernel(const float* __restrict__ W,
                                     ushort_t* __restrict__ Wt,
                                     int K, int N, int n0)
{
    __shared__ float tile[64][65];
    const int tid = threadIdx.x;
    const int k0 = blockIdx.x * 64;
    const int nb = blockIdx.y * 64;
#pragma unroll
    for (int q = 0; q < 4; q++) {
        int r = (tid >> 4) + q * 16;
        int c = (tid & 15) * 4;
        float4 v = *(const float4*)&W[(size_t)(k0 + r) * N + n0 + nb + c];
        tile[r][c + 0] = v.x; tile[r][c + 1] = v.y;
        tile[r][c + 2] = v.z; tile[r][c + 3] = v.w;
    }
    __syncthreads();
#pragma unroll
    for (int q = 0; q < 4; q++) {
        int rn = (tid >> 4) + q * 16;
        int ck = (tid & 15) * 4;
        ushort4 o;
        o.x = bf16_rne(tile[ck + 0][rn]);
        o.y = bf16_rne(tile[ck + 1][rn]);
        o.z = bf16_rne(tile[ck + 2][rn]);
        o.w = bf16_rne(tile[ck + 3][rn]);
        *(ushort4*)&Wt[(size_t)(nb + rn) * K + k0 + ck] = o;
    }
}

// ---------------- pack fc8 weights: [4096,20]x2 -> bf16 [128][4096] --------
__launch_bounds__(256)
__global__ void pack_w8_kernel(const float* __restrict__ cw,
                               const float* __restrict__ dw,
                               ushort_t* __restrict__ Wt8)
{
    int idx = blockIdx.x * 256 + threadIdx.x;  // 128*4096 total
    int n = idx >> 12, k = idx & 4095;
    float v = 0.f;
    if (n < NCL) v = cw[(size_t)k * NCL + n];
    else if (n < 2 * NCL) v = dw[(size_t)k * NCL + (n - NCL)];
    Wt8[(size_t)n * 4096 + k] = bf16_rne(v);
}

__launch_bounds__(128)
__global__ void pack_b8_kernel(const float* __restrict__ cb,
                               const float* __restrict__ db,
                               float* __restrict__ b8)
{
    int n = threadIdx.x;
    float v = 0.f;
    if (n < NCL) v = cb[n];
    else if (n < 2 * NCL) v = db[n - NCL];
    b8[n] = v;
}

// ---------------- bf16 MFMA GEMM (m97 + 2-phase dbuf + kg-major LDS) -------
// A [M,K] bf16 row-major, Bt [Nsub,K] bf16 row-major (= B^T), C row stride Nc.
// Tile 128x128, BK=32, 4 waves x (4x4) 16x16x32 tiles. bias(+relu) epilogue.
// LDS layout: chunk s in [0,512) = [kg = s>>7][m = s&127], chunk = 8 bf16.
// global_load_lds dest is linear (slot = tid); SOURCE is permuted to match
// (rule 21). K-offsets are 64B-aligned so each row's 4 kg chunks share a line.
// Fragment read: consecutive 16B chunks per 16-lane group -> conflict-free.
#define GEMM_STAGE(buf, kb)                                                              \
    gl_lds16(&A[(size_t)(mBase + (tid & 127)) * K + (kb) + (tid >> 7) * 8],              \
             &As[buf][tid * 8]);                                                         \
    gl_lds16(&A[(size_t)(mBase + (tid & 127)) * K + (kb) + ((tid >> 7) + 2) * 8],        \
             &As[buf][(256 + tid) * 8]);                                                 \
    gl_lds16(&Bt[(size_t)(nBase + (tid & 127)) * K + (kb) + (tid >> 7) * 8],             \
             &Bs[buf][tid * 8]);                                                         \
    gl_lds16(&Bt[(size_t)(nBase + (tid & 127)) * K + (kb) + ((tid >> 7) + 2) * 8],       \
             &Bs[buf][(256 + tid) * 8]);

template <bool OUT_BF16, bool RELU>
__launch_bounds__(256)
__global__ void gemm_bt_kernel(const ushort_t* __restrict__ A,
                               const ushort_t* __restrict__ Bt,
                               const float* __restrict__ bias,
                               void* __restrict__ Cv,
                               int Nc, int K)
{
    __shared__ ushort_t As[2][128 * 32];
    __shared__ ushort_t Bs[2][128 * 32];
    const int tid = threadIdx.x;
    const int w = tid >> 6, l = tid & 63;

    // bijective XCD swizzle (m204) on column-major linear tile id:
    // consecutive-per-XCD chunk = few N-columns x all M-rows (A-panel shared).
    const int nwg = gridDim.x * gridDim.y;
    const int hwid = blockIdx.y * gridDim.x + blockIdx.x;  // dispatch order
    const int q = nwg >> 3, r = nwg & 7;
    const int xcd = hwid & 7, i0 = hwid >> 3;
    const int swz = (xcd < r ? xcd * (q + 1) : r * (q + 1) + (xcd - r) * q) + i0;
    const int nBase = (swz / gridDim.y) * 128;
    const int mBase = (swz % gridDim.y) * 128;
    const int mW = (w >> 1) * 64, nW = (w & 1) * 64;

    floatx4 acc[4][4];
#pragma unroll
    for (int i = 0; i < 4; i++)
#pragma unroll
        for (int j = 0; j < 4; j++) acc[i][j] = (floatx4){0.f, 0.f, 0.f, 0.f};

    GEMM_STAGE(0, 0);
    asm volatile("s_waitcnt vmcnt(0)" ::: "memory");
    __syncthreads();

    int cur = 0;
    for (int kb = 0; kb < K; kb += 32) {
        if (kb + 32 < K) { GEMM_STAGE(cur ^ 1, kb + 32); }

        short8 aF[4], bF[4];
#pragma unroll
        for (int i = 0; i < 4; i++)
            aF[i] = *(const short8*)&As[cur][((l >> 4) * 128 + mW + i * 16 + (l & 15)) * 8];
#pragma unroll
        for (int j = 0; j < 4; j++)
            bF[j] = *(const short8*)&Bs[cur][((l >> 4) * 128 + nW + j * 16 + (l & 15)) * 8];
#pragma unroll
        for (int i = 0; i < 4; i++)
#pragma unroll
            for (int j = 0; j < 4; j++)
                acc[i][j] = __builtin_amdgcn_mfma_f32_16x16x32_bf16(aF[i], bF[j], acc[i][j], 0, 0, 0);

        asm volatile("s_waitcnt vmcnt(0)" ::: "memory");
        __syncthreads();
        cur ^= 1;
    }

#pragma unroll
    for (int i = 0; i < 4; i++) {
        int rowT = mBase + mW + i * 16 + (l >> 4) * 4;
#pragma unroll
        for (int j = 0; j < 4; j++) {
            int col = nBase + nW + j * 16 + (l & 15);
            float bv = bias[col];
#pragma unroll
            for (int r2 = 0; r2 < 4; r2++) {
                float v = acc[i][j][r2] + bv;
                if (RELU) v = v > 0.f ? v : 0.f;
                size_t idx = (size_t)(rowT + r2) * Nc + col;
                if (OUT_BF16) ((ushort_t*)Cv)[idx] = bf16_rne(v);
                else ((float*)Cv)[idx] = v;
            }
        }
    }
}

// ---------------- softmax column stats over fp32 logits --------------------
// logits layout: [KTOP][128]; cols 0..19 = c-stream, 20..39 = d-stream
__launch_bounds__(256)
__global__ void colstats_kernel(const float* __restrict__ logits,
                                double* __restrict__ cmax, double* __restrict__ csum)
{
    __shared__ double red[4];
    int j = blockIdx.x, tid = threadIdx.x;
    double m = -1.0e300;
    for (int i = tid; i < KTOP; i += 256) m = fmax(m, (double)logits[(size_t)i * 128 + j]);
    for (int off = 32; off > 0; off >>= 1) m = fmax(m, __shfl_down(m, off, 64));
    if ((tid & 63) == 0) red[tid >> 6] = m;
    __syncthreads();
    double mm = fmax(fmax(red[0], red[1]), fmax(red[2], red[3]));
    __syncthreads();
    double s = 0.0;
    for (int i = tid; i < KTOP; i += 256) s += exp((double)logits[(size_t)i * 128 + j] - mm);
    for (int off = 32; off > 0; off >>= 1) s += __shfl_down(s, off, 64);
    if ((tid & 63) == 0) red[tid >> 6] = s;
    __syncthreads();
    if (tid == 0) { cmax[j] = mm; csum[j] = red[0] + red[1] + red[2] + red[3]; }
}

// ---------------- row softmax + scores ---------------------------------------
__launch_bounds__(256)
__global__ void scores_kernel(const float* __restrict__ logits,
                              const double* __restrict__ cmax, const double* __restrict__ csum,
                              double* __restrict__ scd, float* __restrict__ outScores)
{
    int i = blockIdx.x * 256 + threadIdx.x;
    if (i >= KTOP) return;
    const float* lr = logits + (size_t)i * 128;
    double rm = -1.0e300;
#pragma unroll
    for (int j = 0; j < NCL; j++) rm = fmax(rm, (double)lr[NCL + j]);
    double rs = 0.0;
#pragma unroll
    for (int j = 0; j < NCL; j++) rs += exp((double)lr[NCL + j] - rm);
#pragma unroll
    for (int j = 0; j < NCL; j++) {
        double cc = exp((double)lr[j] - cmax[j]) / csum[j];
        double dd = exp((double)lr[NCL + j] - rm) / rs;
        double sc = cc * dd;
        scd[(size_t)i * NCL + j] = sc;
        outScores[(size_t)i * NCL + j] = (float)sc;
    }
}

// ---------------- column sum + clip -----------------------------------------
__launch_bounds__(256)
__global__ void colsum_kernel(const double* __restrict__ scd, float* __restrict__ out)
{
    __shared__ double red[4];
    int j = blockIdx.x, tid = threadIdx.x;
    double s = 0.0;
    for (int i = tid; i < KTOP; i += 256) s += scd[(size_t)i * NCL + j];
    for (int off = 32; off > 0; off >>= 1) s += __shfl_down(s, off, 64);
    if ((tid & 63) == 0) red[tid >> 6] = s;
    __syncthreads();
    if (tid == 0) {
        double t = red[0] + red[1] + red[2] + red[3];
        t = t < 0.0 ? 0.0 : (t > 1.0 ? 1.0 : t);
        out[j] = (float)t;
    }
}

// ---------------------------------------------------------------------------
extern "C" void kernel_launch(void* const* d_in, const int* in_sizes, int n_in,
                              void* d_out, int out_size, void* d_ws, size_t ws_size,
                              hipStream_t stream)
{
    const float* features = (const float*)d_in[0];
    const float* rpn_w  = (const float*)d_in[2];
    const float* rpn_b  = (const float*)d_in[3];
    const float* cls_w  = (const float*)d_in[4];
    const float* cls_b  = (const float*)d_in[5];
    const float* reg_w  = (const float*)d_in[6];
    const float* reg_b  = (const float*)d_in[7];
    const float* fc6_w  = (const float*)d_in[8];
    const float* fc6_b  = (const float*)d_in[9];
    const float* fc7_w  = (const float*)d_in[10];
    const float* fc7_b  = (const float*)d_in[11];
    const float* fc8c_w = (const float*)d_in[12];
    const float* fc8c_b = (const float*)d_in[13];
    const float* fc8d_w = (const float*)d_in[14];
    const float* fc8d_b = (const float*)d_in[15];

    float* out = (float*)d_out;
    char* ws = (char*)d_ws;

    // ---- workspace layout (phase-overlapped; peak ~99 MB) ----
    const size_t OFF_H6   = 0;
    const size_t OFF_WT   = 37748736;
    const size_t OFF_ABF  = 80216064;
    const size_t OFF_H7   = 80216064;
    // early smalls (inside h6bf region):
    const size_t OFF_X32  = 0;
    const size_t OFF_KEY  = 5120000;
    const size_t OFF_CNT  = 5210112;
    const size_t OFF_SORT = 5300224;
    const size_t OFF_BOXD = 5308416;
    // late smalls (WtBuf tail, free during/after GEMM2):
    const size_t OFF_LOGIT = OFF_WT + 37748736;          // 2048*128*4 = 1,048,576
    const size_t OFF_W8T   = OFF_LOGIT + 1048576;        // 128*4096*2 = 1,048,576
    const size_t OFF_B8    = OFF_W8T + 1048576;          // 512
    const size_t OFF_SCD   = OFF_B8 + 512;               // 327,680
    const size_t OFF_CMAX  = OFF_SCD + 327680;           // 512
    const size_t OFF_CSUM  = OFF_CMAX + 512;             // 512

    float*    x32    = (float*)(ws + OFF_X32);
    float*    key    = (float*)(ws + OFF_KEY);
    int*      cnt    = (int*)(ws + OFF_CNT);
    int*      sorted = (int*)(ws + OFF_SORT);
    double*   boxd   = (double*)(ws + OFF_BOXD);
    ushort_t* Abf    = (ushort_t*)(ws + OFF_ABF);
    ushort_t* Wt     = (ushort_t*)(ws + OFF_WT);
    ushort_t* h6bf   = (ushort_t*)(ws + OFF_H6);
    ushort_t* h7bf   = (ushort_t*)(ws + OFF_H7);
    float*    logits = (float*)(ws + OFF_LOGIT);
    ushort_t* Wt8    = (ushort_t*)(ws + OFF_W8T);
    float*    b8     = (float*)(ws + OFF_B8);
    double*   scd    = (double*)(ws + OFF_SCD);
    double*   cmax   = (double*)(ws + OFF_CMAX);
    double*   csum   = (double*)(ws + OFF_CSUM);

    float* outScores = out + NCL;
    float* outBoxes  = out + NCL + KTOP * NCL;

    // 1-4: bit-exact RPN path (conv v3: same chains, grid (625,2), no LDS)
    conv_chain_kernel<<<dim3(625, 2), 256, 0, stream>>>(features, rpn_w, rpn_b, x32);
    obj_chain_kernel<<<dim3(88), 256, 0, stream>>>(x32, cls_w, cls_b, key);
    hipMemsetAsync(cnt, 0, NOBJ * sizeof(int), stream);
    topk_count_kernel<<<dim3(88, 11), 256, 0, stream>>>(key, cnt);
    topk_scatter_kernel<<<dim3(88), 256, 0, stream>>>(cnt, sorted);
    boxes_kernel<<<dim3(8), 256, 0, stream>>>(sorted, x32, reg_w, reg_b, boxd, outBoxes);

    // 5: ROI align -> Abf (bf16)
    roi_kernel<<<dim3(KTOP), 256, 0, stream>>>(features, boxd, Abf);

    // 6: fc6 = Abf[2048,4608] x fc6_w[4608,9216] (+relu) -> h6bf, two N-halves
    transpose_cvt_kernel<<<dim3(72, 72), 256, 0, stream>>>(fc6_w, Wt, 4608, 9216, 0);
    gemm_bt_kernel<true, true><<<dim3(36, 16), 256, 0, stream>>>(Abf, Wt, fc6_b + 0,
                                                                 (void*)(h6bf + 0), 9216, 4608);
    transpose_cvt_kernel<<<dim3(72, 72), 256, 0, stream>>>(fc6_w, Wt, 4608, 9216, 4608);
    gemm_bt_kernel<true, true><<<dim3(36, 16), 256, 0, stream>>>(Abf, Wt, fc6_b + 4608,
                                                                 (void*)(h6bf + 4608), 9216, 4608);

    // 7: fc7 = h6bf[2048,9216] x fc7_w[9216,4096] (+relu) -> h7bf, two halves
    transpose_cvt_kernel<<<dim3(144, 32), 256, 0, stream>>>(fc7_w, Wt, 9216, 4096, 0);
    gemm_bt_kernel<true, true><<<dim3(16, 16), 256, 0, stream>>>(h6bf, Wt, fc7_b + 0,
                                                                 (void*)(h7bf + 0), 4096, 9216);
    transpose_cvt_kernel<<<dim3(144, 32), 256, 0, stream>>>(fc7_w, Wt, 9216, 4096, 2048);
    gemm_bt_kernel<true, true><<<dim3(16, 16), 256, 0, stream>>>(h6bf, Wt, fc7_b + 2048,
                                                                 (void*)(h7bf + 2048), 4096, 9216);

    // 8: fc8 both streams as one MFMA GEMM: h7bf[2048,4096] x Wt8^T -> logits[2048,128]
    pack_w8_kernel<<<dim3(2048), 256, 0, stream>>>(fc8c_w, fc8d_w, Wt8);
    pack_b8_kernel<<<dim3(1), 128, 0, stream>>>(fc8c_b, fc8d_b, b8);
    gemm_bt_kernel<false, false><<<dim3(1, 16), 256, 0, stream>>>(h7bf, Wt8, b8,
                                                                  (void*)logits, 128, 4096);

    // 9: softmaxes + scores + clipped colsum
    colstats_kernel<<<dim3(NCL), 256, 0, stream>>>(logits, cmax, csum);
    scores_kernel<<<dim3(8), 256, 0, stream>>>(logits, cmax, csum, scd, outScores);
    colsum_kernel<<<dim3(NCL), 256, 0, stream>>>(scd, out);
}

// Round 3
// 1797.483 us; speedup vs baseline: 1.0385x; 1.0385x over previous
//
#include <hip/hip_runtime.h>
#include <math.h>

// ---------------------------------------------------------------------------
// WeaklySupervisedDetection
//   Phases 1-4 (conv/obj/topk/boxes): f32-bit-exact chains — DO NOT TOUCH the
//   arithmetic ORDER; they reproduce the np reference's ordering.
//   conv v4 = round-1 v2 (LDS x staging, b128 quad reads, 2 co/thread,
//   grid 625) + explicit weight double-buffer prefetch (bit-exact order).
//   GEMMs: kg-major conflict-free LDS (rule 21), 3-buffer 2-deep pipeline
//   with counted vmcnt(4) + raw s_barrier + sched_barrier(0) (T3+T4),
//   bijective XCD swizzle (T1). fc8 split-K x8 + deterministic reduce.
//   Softmaxes: fp64 math over fp32 logits (tiny kernels).
// ---------------------------------------------------------------------------

#define HN 50
#define WN 50
#define CN 512
#define AN 9
#define KTOP 2048
#define NCL 20
#define NOBJ 22500  // H*W*A

typedef unsigned short ushort_t;
typedef __attribute__((ext_vector_type(8))) short short8;
typedef __attribute__((ext_vector_type(4))) float floatx4;

__device__ __forceinline__ ushort_t bf16_rne(float f) {
    unsigned int u = __float_as_uint(f);
    unsigned int r = (u + 0x7FFFu + ((u >> 16) & 1u)) >> 16;
    return (ushort_t)r;
}

__device__ __forceinline__ void gl_lds16(const void* g, void* l) {
    __builtin_amdgcn_global_load_lds(
        (const __attribute__((address_space(1))) unsigned int*)g,
        (__attribute__((address_space(3))) unsigned int*)l, 16, 0, 0);
}

// ---------------- conv 2x2 SAME, exact f32 tap chains ----------------------
// v4: 256 threads, each owns co pair (2*tid, 2*tid+1). 4 hw positions/block,
// grid 625. Per c-quad: 16x ds_read_b128 broadcast (x), 16x float2 coalesced
// weights — double-buffered so quad k+1's loads overlap quad k's 128 FMAs.
// Chain per output identical to v1/v2: c ascending, one fmaf per c, taps
// combined ((t0+t1)+t2)+t3 + b, relu.
__launch_bounds__(256)
__global__ void conv_chain_kernel(const float* __restrict__ feat,
                                  const float* __restrict__ rpnw,
                                  const float* __restrict__ rpnb,
                                  float* __restrict__ x32)
{
    __shared__ float xs[16 * 512];  // [slot(4hw x 4tap)][cin(512)] = 32 KB
    const int tid = threadIdx.x;
    const int hwBase = blockIdx.x * 4;
    const int co0 = tid * 2;

    // staging: float4 global -> b128 LDS, zero-pad edges
    for (int t = tid; t < 16 * 128; t += 256) {
        int slot = t >> 7, q = t & 127;
        int hwL = slot >> 2, tap = slot & 3;
        int hw = hwBase + hwL;
        int h = hw / WN, w = hw % WN;
        int hy = h + (tap >> 1), wx = w + (tap & 1);
        float4 v = make_float4(0.f, 0.f, 0.f, 0.f);
        if (hy < HN && wx < WN)
            v = *(const float4*)&feat[(size_t)(hy * WN + wx) * CN + q * 4];
        *(float4*)&xs[slot * 512 + q * 4] = v;
    }
    __syncthreads();

    float accx[4][4];  // [i][tap] for co0
    float accy[4][4];  // [i][tap] for co0+1
#pragma unroll
    for (int i = 0; i < 4; i++)
#pragma unroll
        for (int t = 0; t < 4; t++) { accx[i][t] = 0.f; accy[i][t] = 0.f; }

    const float* wbase = rpnw + co0;

    float2 wA[4][4], wB[4][4];  // [cc][tap]

    auto loadw = [&](float2 (&wd)[4][4], int cqv) {
#pragma unroll
        for (int cc = 0; cc < 4; cc++)
#pragma unroll
            for (int t = 0; t < 4; t++)
                wd[cc][t] = *(const float2*)&wbase[(size_t)(t * CN + cqv + cc) * CN];
    };

    auto dofma = [&](const float2 (&wd)[4][4], int cqv) {
        float4 xv[4][4];
#pragma unroll
        for (int i = 0; i < 4; i++)
#pragma unroll
            for (int t = 0; t < 4; t++)
                xv[i][t] = *(const float4*)&xs[(i * 4 + t) * 512 + cqv];
#pragma unroll
        for (int cc = 0; cc < 4; cc++)
#pragma unroll
            for (int i = 0; i < 4; i++)
#pragma unroll
                for (int t = 0; t < 4; t++) {
                    float xvv = cc == 0 ? xv[i][t].x
                              : cc == 1 ? xv[i][t].y
                              : cc == 2 ? xv[i][t].z : xv[i][t].w;
                    accx[i][t] = fmaf(xvv, wd[cc][t].x, accx[i][t]);
                    accy[i][t] = fmaf(xvv, wd[cc][t].y, accy[i][t]);
                }
    };

    loadw(wA, 0);
    for (int cq = 0; cq < CN - 8; cq += 8) {
        loadw(wB, cq + 4);
        dofma(wA, cq);
        loadw(wA, cq + 8);
        dofma(wB, cq + 4);
    }
    loadw(wB, CN - 4);
    dofma(wA, CN - 8);
    dofma(wB, CN - 4);

    float b0 = rpnb[co0], b1 = rpnb[co0 + 1];
#pragma unroll
    for (int i = 0; i < 4; i++) {
        float v0 = ((accx[i][0] + accx[i][1]) + accx[i][2]) + accx[i][3];
        float v1 = ((accy[i][0] + accy[i][1]) + accy[i][2]) + accy[i][3];
        v0 = v0 + b0; v1 = v1 + b1;
        v0 = v0 > 0.f ? v0 : 0.f;
        v1 = v1 > 0.f ? v1 : 0.f;
        float2 o = make_float2(v0, v1);
        *(float2*)&x32[(size_t)(hwBase + i) * CN + co0] = o;
    }
}

// ---------------- objectness: f32 chain -> f32 sigmoid key ------------------
__launch_bounds__(256)
__global__ void obj_chain_kernel(const float* __restrict__ x32,
                                 const float* __restrict__ clsw,
                                 const float* __restrict__ clsb,
                                 float* __restrict__ key)
{
    int i = blockIdx.x * 256 + threadIdx.x;
    if (i >= NOBJ) return;
    int hw = i / AN, a = i % AN;
    const float* xr = x32 + (size_t)hw * CN;
    float acc = 0.f;
    for (int c = 0; c < CN; c++) acc = fmaf(xr[c], clsw[c * AN + a], acc);
    float l32 = acc + clsb[a];
    float s32 = (float)(1.0 / (1.0 + exp(-(double)l32)));
    key[i] = s32;
}

// ---------------- exact top-K rank count on (f32 key desc, idx asc) --------
__launch_bounds__(256)
__global__ void topk_count_kernel(const float* __restrict__ key, int* __restrict__ cnt)
{
    __shared__ float ch[2048];
    int tid = threadIdx.x;
    int j0 = blockIdx.y * 2048;
    for (int t = tid; t < 2048; t += 256) {
        int jg = j0 + t;
        ch[t] = (jg < NOBJ) ? key[jg] : -1.0f;
    }
    int i = blockIdx.x * 256 + tid;
    float vi = (i < NOBJ) ? key[i] : 2.0f;
    __syncthreads();
    int c = 0;
    for (int t = 0; t < 2048; t++) {
        float vj = ch[t];
        int jg = j0 + t;
        c += (vj > vi || (vj == vi && jg < i)) ? 1 : 0;
    }
    if (i < NOBJ && c) atomicAdd(&cnt[i], c);
}

__launch_bounds__(256)
__global__ void topk_scatter_kernel(const int* __restrict__ cnt, int* __restrict__ sorted)
{
    int i = blockIdx.x * 256 + threadIdx.x;
    if (i < NOBJ) {
        int r = cnt[i];
        if (r < KTOP) sorted[r] = i;
    }
}

// ---------------- box regression (f32 chains) + transform (fp64) -----------
__launch_bounds__(256)
__global__ void boxes_kernel(const int* __restrict__ sorted,
                             const float* __restrict__ x32,
                             const float* __restrict__ regw,
                             const float* __restrict__ regb,
                             double* __restrict__ boxd,
                             float* __restrict__ outBoxes)
{
    int k = blockIdx.x * 256 + threadIdx.x;
    if (k >= KTOP) return;
    int i = sorted[k];
    int hw = i / AN, a = i % AN;
    const float* xr = x32 + (size_t)hw * CN;
    float r0 = 0.f, r1 = 0.f, r2 = 0.f, r3 = 0.f;
    for (int c = 0; c < CN; c++) {
        float xv = xr[c];
        const float* wr = regw + (size_t)c * (4 * AN) + 4 * a;
        r0 = fmaf(xv, wr[0], r0);
        r1 = fmaf(xv, wr[1], r1);
        r2 = fmaf(xv, wr[2], r2);
        r3 = fmaf(xv, wr[3], r3);
    }
    r0 = r0 + regb[4 * a + 0];
    r1 = r1 + regb[4 * a + 1];
    r2 = r2 + regb[4 * a + 2];
    r3 = r3 + regb[4 * a + 3];
    double s0 = 1.0 / (1.0 + exp(-(double)r0));
    double s1 = 1.0 / (1.0 + exp(-(double)r1));
    double s2 = 1.0 / (1.0 + exp(-(double)r2));
    double s3 = 1.0 / (1.0 + exp(-(double)r3));
    double x1 = s0 * (double)(WN - 2);
    double x2 = x1 + 1.0 + s1 * ((double)(WN - 1) - x1);
    double y1 = s2 * (double)(HN - 2);
    double y2 = y1 + 1.0 + s3 * ((double)(HN - 1) - y1);
    boxd[4 * k + 0] = x1; boxd[4 * k + 1] = x2;
    boxd[4 * k + 2] = y1; boxd[4 * k + 3] = y2;
    outBoxes[4 * k + 0] = (float)x1; outBoxes[4 * k + 1] = (float)x2;
    outBoxes[4 * k + 2] = (float)y1; outBoxes[4 * k + 3] = (float)y2;
}

// ---------------- ROI align -> pooled [K, 4608] (bf16) ---------------------
__launch_bounds__(256)
__global__ void roi_kernel(const float* __restrict__ feat,
                           const double* __restrict__ boxd,
                           ushort_t* __restrict__ pooled)
{
    int k = blockIdx.x;
    int tid = threadIdx.x;
    double x1 = boxd[4 * k + 0], x2 = boxd[4 * k + 1];
    double y1 = boxd[4 * k + 2], y2 = boxd[4 * k + 3];
    int ix0[3], ix1[3], iy0[3], iy1[3];
    double fx[3], fy[3];
#pragma unroll
    for (int p = 0; p < 3; p++) {
        double t = ((double)p + 0.5) / 3.0;
        double xsv = x1 + (x2 - x1) * t;
        double x0f = floor(xsv);
        fx[p] = xsv - x0f;
        int xi = (int)x0f;
        xi = xi < 0 ? 0 : (xi > WN - 1 ? WN - 1 : xi);
        ix0[p] = xi;
        ix1[p] = (xi + 1 > WN - 1) ? WN - 1 : xi + 1;
        double ysv = y1 + (y2 - y1) * t;
        double y0f = floor(ysv);
        fy[p] = ysv - y0f;
        int yi = (int)y0f;
        yi = yi < 0 ? 0 : (yi > HN - 1 ? HN - 1 : yi);
        iy0[p] = yi;
        iy1[p] = (yi + 1 > HN - 1) ? HN - 1 : yi + 1;
    }
#pragma unroll
    for (int pp = 0; pp < 9; pp++) {
        int py = pp / 3, px = pp % 3;
        double w00 = (1.0 - fy[py]) * (1.0 - fx[px]);
        double w01 = (1.0 - fy[py]) * fx[px];
        double w10 = fy[py] * (1.0 - fx[px]);
        double w11 = fy[py] * fx[px];
        const float* f00 = feat + (size_t)(iy0[py] * WN + ix0[px]) * CN;
        const float* f01 = feat + (size_t)(iy0[py] * WN + ix1[px]) * CN;
        const float* f10 = feat + (size_t)(iy1[py] * WN + ix0[px]) * CN;
        const float* f11 = feat + (size_t)(iy1[py] * WN + ix1[px]) * CN;
        ushort_t* dst = pooled + ((size_t)k * 9 + pp) * CN;
        for (int c = tid; c < CN; c += 256) {
            double v = w00 * (double)f00[c] + w01 * (double)f01[c]
                     + w10 * (double)f10[c] + w11 * (double)f11[c];
            dst[c] = bf16_rne((float)v);
        }
    }
}

// ---------------- transpose + cvt: W fp32 [K,N] cols [n0,n0+Nsub) ----------
//                  -> Wt bf16 [Nsub][K]
__launch_bounds__(256)
__global__ void transpose_cvt_kernel(const float* __restrict__ W,
                                     ushort_t* __restrict__ Wt,
                                     int K, int N, int n0)
{
    __shared__ float tile[64][65];
    const int tid = threadIdx.x;
    const int k0 = blockIdx.x * 64;
    const int nb = blockIdx.y * 64;
#pragma unroll
    for (int q = 0; q < 4; q++) {
        int r = (tid >> 4) + q * 16;
        int c = (tid & 15) * 4;
        float4 v = *(const float4*)&W[(size_t)(k0 + r) * N + n0 + nb + c];
        tile[r][c + 0] = v.x; tile[r][c + 1] = v.y;
        tile[r][c + 2] = v.z; tile[r][c + 3] = v.w;
    }
    __syncthreads();
#pragma unroll
    for (int q = 0; q < 4; q++) {
        int rn = (tid >> 4) + q * 16;
        int ck = (tid & 15) * 4;
        ushort4 o;
        o.x = bf16_rne(tile[ck + 0][rn]);
        o.y = bf16_rne(tile[ck + 1][rn]);
        o.z = bf16_rne(tile[ck + 2][rn]);
        o.w = bf16_rne(tile[ck + 3][rn]);
        *(ushort4*)&Wt[(size_t)(nb + rn) * K + k0 + ck] = o;
    }
}

// ---------------- pack fc8 weights: [4096,20]x2 -> bf16 [128][4096] --------
__launch_bounds__(256)
__global__ void pack_w8_kernel(const float* __restrict__ cw,
                               const float* __restrict__ dw,
                               ushort_t* __restrict__ Wt8)
{
    int idx = blockIdx.x * 256 + threadIdx.x;  // 128*4096 total
    int n = idx >> 12, k = idx & 4095;
    float v = 0.f;
    if (n < NCL) v = cw[(size_t)k * NCL + n];
    else if (n < 2 * NCL) v = dw[(size_t)k * NCL + (n - NCL)];
    Wt8[(size_t)n * 4096 + k] = bf16_rne(v);
}

__launch_bounds__(128)
__global__ void pack_b8_kernel(const float* __restrict__ cb,
                               const float* __restrict__ db,
                               float* __restrict__ b8)
{
    int n = threadIdx.x;
    float v = 0.f;
    if (n < NCL) v = cb[n];
    else if (n < 2 * NCL) v = db[n - NCL];
    b8[n] = v;
}

// ---------------- bf16 MFMA GEMM (kg-major LDS, 3-buf 2-deep pipeline) -----
// A [M,Krow] bf16 row-major, Bt [Nsub,Krow] bf16 row-major (= B^T), C row
// stride Nc. Tile 128x128, BK=32, 4 waves x (4x4) 16x16x32 tiles.
// LDS chunk s in [0,512) = [kg = s>>7][m = s&127], chunk = 8 bf16; dest is
// linear (slot = tid), SOURCE permuted to match (rule 21). Fragment reads:
// 16 consecutive 16B chunks per 16-lane group -> conflict-free.
// Pipeline: 3 buffers; stage(i+2) issued post-barrier(i); counted vmcnt(4)
// (never drains in main loop); raw s_barrier + sched_barrier(0).
// SPLITK: grid.z chunks of kLen, f32 partials (no bias), reduce adds bias.
#define GEMM_STAGE(buf, kb)                                                                 \
    gl_lds16(&A[(size_t)(mBase + (tid & 127)) * Krow + (kb) + (tid >> 7) * 8],              \
             &As[buf][tid * 8]);                                                            \
    gl_lds16(&A[(size_t)(mBase + (tid & 127)) * Krow + (kb) + ((tid >> 7) + 2) * 8],        \
             &As[buf][(256 + tid) * 8]);                                                    \
    gl_lds16(&Bt[(size_t)(nBase + (tid & 127)) * Krow + (kb) + (tid >> 7) * 8],             \
             &Bs[buf][tid * 8]);                                                            \
    gl_lds16(&Bt[(size_t)(nBase + (tid & 127)) * Krow + (kb) + ((tid >> 7) + 2) * 8],       \
             &Bs[buf][(256 + tid) * 8]);

template <bool OUT_BF16, bool RELU, bool SPLITK>
__launch_bounds__(256)
__global__ void gemm_bt_kernel(const ushort_t* __restrict__ A,
                               const ushort_t* __restrict__ Bt,
                               const float* __restrict__ bias,
                               void* __restrict__ Cv,
                               int Nc, int Krow, int kLen)
{
    __shared__ ushort_t As[3][128 * 32];
    __shared__ ushort_t Bs[3][128 * 32];
    const int tid = threadIdx.x;
    const int w = tid >> 6, l = tid & 63;

    // bijective XCD swizzle (m204) on column-major linear tile id
    const int nwg = gridDim.x * gridDim.y;
    const int hwid = blockIdx.y * gridDim.x + blockIdx.x;
    const int q = nwg >> 3, r = nwg & 7;
    const int xcd = hwid & 7, i0 = hwid >> 3;
    const int swz = (xcd < r ? xcd * (q + 1) : r * (q + 1) + (xcd - r) * q) + i0;
    const int nBase = (swz / gridDim.y) * 128;
    const int mBase = (swz % gridDim.y) * 128;
    const int mW = (w >> 1) * 64, nW = (w & 1) * 64;

    const int kb0 = SPLITK ? blockIdx.z * kLen : 0;
    const int T = kLen / 32;

    floatx4 acc[4][4];
#pragma unroll
    for (int i = 0; i < 4; i++)
#pragma unroll
        for (int j = 0; j < 4; j++) acc[i][j] = (floatx4){0.f, 0.f, 0.f, 0.f};

    GEMM_STAGE(0, kb0);
    GEMM_STAGE(1, kb0 + 32);

    int cur = 0, nxt2 = 2;
    for (int it = 0; it < T; ++it) {
        if (it + 1 < T) asm volatile("s_waitcnt vmcnt(4)" ::: "memory");
        else            asm volatile("s_waitcnt vmcnt(0)" ::: "memory");
        __builtin_amdgcn_s_barrier();
        __builtin_amdgcn_sched_barrier(0);
        if (it + 2 < T) { GEMM_STAGE(nxt2, kb0 + (it + 2) * 32); }

        short8 aF[4], bF[4];
#pragma unroll
        for (int i = 0; i < 4; i++)
            aF[i] = *(const short8*)&As[cur][((l >> 4) * 128 + mW + i * 16 + (l & 15)) * 8];
#pragma unroll
        for (int j = 0; j < 4; j++)
            bF[j] = *(const short8*)&Bs[cur][((l >> 4) * 128 + nW + j * 16 + (l & 15)) * 8];
#pragma unroll
        for (int i = 0; i < 4; i++)
#pragma unroll
            for (int j = 0; j < 4; j++)
                acc[i][j] = __builtin_amdgcn_mfma_f32_16x16x32_bf16(aF[i], bF[j], acc[i][j], 0, 0, 0);

        cur = (cur == 2) ? 0 : cur + 1;
        nxt2 = (nxt2 == 2) ? 0 : nxt2 + 1;
    }

    float* Cp = (float*)Cv;
    if (SPLITK) Cp += (size_t)blockIdx.z * (size_t)gridDim.y * 128 * Nc;

#pragma unroll
    for (int i = 0; i < 4; i++) {
        int rowT = mBase + mW + i * 16 + (l >> 4) * 4;
#pragma unroll
        for (int j = 0; j < 4; j++) {
            int col = nBase + nW + j * 16 + (l & 15);
            float bv = SPLITK ? 0.f : bias[col];
#pragma unroll
            for (int r2 = 0; r2 < 4; r2++) {
                float v = acc[i][j][r2] + bv;
                if (RELU) v = v > 0.f ? v : 0.f;
                size_t idx = (size_t)(rowT + r2) * Nc + col;
                if (OUT_BF16) ((ushort_t*)Cv)[idx] = bf16_rne(v);
                else Cp[idx] = v;
            }
        }
    }
}

// ---------------- fc8 split-K reduce: logits = sum_s P[s] + bias -----------
__launch_bounds__(256)
__global__ void reduce8_kernel(const float* __restrict__ P,
                               const float* __restrict__ b8,
                               float* __restrict__ logits)
{
    int idx = blockIdx.x * 256 + threadIdx.x;  // 2048*128 total
    int j = idx & 127;
    float s = 0.f;
#pragma unroll
    for (int c = 0; c < 8; c++) s += P[(size_t)c * KTOP * 128 + idx];
    logits[idx] = s + b8[j];
}

// ---------------- softmax column stats over fp32 logits --------------------
// logits layout: [KTOP][128]; cols 0..19 = c-stream, 20..39 = d-stream
__launch_bounds__(256)
__global__ void colstats_kernel(const float* __restrict__ logits,
                                double* __restrict__ cmax, double* __restrict__ csum)
{
    __shared__ double red[4];
    int j = blockIdx.x, tid = threadIdx.x;
    double m = -1.0e300;
    for (int i = tid; i < KTOP; i += 256) m = fmax(m, (double)logits[(size_t)i * 128 + j]);
    for (int off = 32; off > 0; off >>= 1) m = fmax(m, __shfl_down(m, off, 64));
    if ((tid & 63) == 0) red[tid >> 6] = m;
    __syncthreads();
    double mm = fmax(fmax(red[0], red[1]), fmax(red[2], red[3]));
    __syncthreads();
    double s = 0.0;
    for (int i = tid; i < KTOP; i += 256) s += exp((double)logits[(size_t)i * 128 + j] - mm);
    for (int off = 32; off > 0; off >>= 1) s += __shfl_down(s, off, 64);
    if ((tid & 63) == 0) red[tid >> 6] = s;
    __syncthreads();
    if (tid == 0) { cmax[j] = mm; csum[j] = red[0] + red[1] + red[2] + red[3]; }
}

// ---------------- row softmax + scores ---------------------------------------
__launch_bounds__(256)
__global__ void scores_kernel(const float* __restrict__ logits,
                              const double* __restrict__ cmax, const double* __restrict__ csum,
                              double* __restrict__ scd, float* __restrict__ outScores)
{
    int i = blockIdx.x * 256 + threadIdx.x;
    if (i >= KTOP) return;
    const float* lr = logits + (size_t)i * 128;
    double rm = -1.0e300;
#pragma unroll
    for (int j = 0; j < NCL; j++) rm = fmax(rm, (double)lr[NCL + j]);
    double rs = 0.0;
#pragma unroll
    for (int j = 0; j < NCL; j++) rs += exp((double)lr[NCL + j] - rm);
#pragma unroll
    for (int j = 0; j < NCL; j++) {
        double cc = exp((double)lr[j] - cmax[j]) / csum[j];
        double dd = exp((double)lr[NCL + j] - rm) / rs;
        double sc = cc * dd;
        scd[(size_t)i * NCL + j] = sc;
        outScores[(size_t)i * NCL + j] = (float)sc;
    }
}

// ---------------- column sum + clip -----------------------------------------
__launch_bounds__(256)
__global__ void colsum_kernel(const double* __restrict__ scd, float* __restrict__ out)
{
    __shared__ double red[4];
    int j = blockIdx.x, tid = threadIdx.x;
    double s = 0.0;
    for (int i = tid; i < KTOP; i += 256) s += scd[(size_t)i * NCL + j];
    for (int off = 32; off > 0; off >>= 1) s += __shfl_down(s, off, 64);
    if ((tid & 63) == 0) red[tid >> 6] = s;
    __syncthreads();
    if (tid == 0) {
        double t = red[0] + red[1] + red[2] + red[3];
        t = t < 0.0 ? 0.0 : (t > 1.0 ? 1.0 : t);
        out[j] = (float)t;
    }
}

// ---------------------------------------------------------------------------
extern "C" void kernel_launch(void* const* d_in, const int* in_sizes, int n_in,
                              void* d_out, int out_size, void* d_ws, size_t ws_size,
                              hipStream_t stream)
{
    const float* features = (const float*)d_in[0];
    const float* rpn_w  = (const float*)d_in[2];
    const float* rpn_b  = (const float*)d_in[3];
    const float* cls_w  = (const float*)d_in[4];
    const float* cls_b  = (const float*)d_in[5];
    const float* reg_w  = (const float*)d_in[6];
    const float* reg_b  = (const float*)d_in[7];
    const float* fc6_w  = (const float*)d_in[8];
    const float* fc6_b  = (const float*)d_in[9];
    const float* fc7_w  = (const float*)d_in[10];
    const float* fc7_b  = (const float*)d_in[11];
    const float* fc8c_w = (const float*)d_in[12];
    const float* fc8c_b = (const float*)d_in[13];
    const float* fc8d_w = (const float*)d_in[14];
    const float* fc8d_b = (const float*)d_in[15];

    float* out = (float*)d_out;
    char* ws = (char*)d_ws;

    // ---- workspace layout (phase-overlapped; peak ~99 MB) ----
    const size_t OFF_H6   = 0;
    const size_t OFF_WT   = 37748736;
    const size_t OFF_ABF  = 80216064;
    const size_t OFF_H7   = 80216064;
    // early smalls (inside h6bf region):
    const size_t OFF_X32  = 0;
    const size_t OFF_KEY  = 5120000;
    const size_t OFF_CNT  = 5210112;
    const size_t OFF_SORT = 5300224;
    const size_t OFF_BOXD = 5308416;
    // fc8 split-K partials: Wt region is dead after fc7 gemms (8 MB used)
    const size_t OFF_P8   = OFF_WT;
    // late smalls (WtBuf tail, free during/after GEMM2):
    const size_t OFF_LOGIT = OFF_WT + 37748736;          // 2048*128*4 = 1,048,576
    const size_t OFF_W8T   = OFF_LOGIT + 1048576;        // 128*4096*2 = 1,048,576
    const size_t OFF_B8    = OFF_W8T + 1048576;          // 512
    const size_t OFF_SCD   = OFF_B8 + 512;               // 327,680
    const size_t OFF_CMAX  = OFF_SCD + 327680;           // 512
    const size_t OFF_CSUM  = OFF_CMAX + 512;             // 512

    float*    x32    = (float*)(ws + OFF_X32);
    float*    key    = (float*)(ws + OFF_KEY);
    int*      cnt    = (int*)(ws + OFF_CNT);
    int*      sorted = (int*)(ws + OFF_SORT);
    double*   boxd   = (double*)(ws + OFF_BOXD);
    ushort_t* Abf    = (ushort_t*)(ws + OFF_ABF);
    ushort_t* Wt     = (ushort_t*)(ws + OFF_WT);
    ushort_t* h6bf   = (ushort_t*)(ws + OFF_H6);
    ushort_t* h7bf   = (ushort_t*)(ws + OFF_H7);
    float*    P8     = (float*)(ws + OFF_P8);
    float*    logits = (float*)(ws + OFF_LOGIT);
    ushort_t* Wt8    = (ushort_t*)(ws + OFF_W8T);
    float*    b8     = (float*)(ws + OFF_B8);
    double*   scd    = (double*)(ws + OFF_SCD);
    double*   cmax   = (double*)(ws + OFF_CMAX);
    double*   csum   = (double*)(ws + OFF_CSUM);

    float* outScores = out + NCL;
    float* outBoxes  = out + NCL + KTOP * NCL;

    // 1-4: bit-exact RPN path (conv v4: v2 structure + weight dbuf prefetch)
    conv_chain_kernel<<<dim3(625), 256, 0, stream>>>(features, rpn_w, rpn_b, x32);
    obj_chain_kernel<<<dim3(88), 256, 0, stream>>>(x32, cls_w, cls_b, key);
    hipMemsetAsync(cnt, 0, NOBJ * sizeof(int), stream);
    topk_count_kernel<<<dim3(88, 11), 256, 0, stream>>>(key, cnt);
    topk_scatter_kernel<<<dim3(88), 256, 0, stream>>>(cnt, sorted);
    boxes_kernel<<<dim3(8), 256, 0, stream>>>(sorted, x32, reg_w, reg_b, boxd, outBoxes);

    // 5: ROI align -> Abf (bf16)
    roi_kernel<<<dim3(KTOP), 256, 0, stream>>>(features, boxd, Abf);

    // 6: fc6 = Abf[2048,4608] x fc6_w[4608,9216] (+relu) -> h6bf, two N-halves
    transpose_cvt_kernel<<<dim3(72, 72), 256, 0, stream>>>(fc6_w, Wt, 4608, 9216, 0);
    gemm_bt_kernel<true, true, false><<<dim3(36, 16), 256, 0, stream>>>(
        Abf, Wt, fc6_b + 0, (void*)(h6bf + 0), 9216, 4608, 4608);
    transpose_cvt_kernel<<<dim3(72, 72), 256, 0, stream>>>(fc6_w, Wt, 4608, 9216, 4608);
    gemm_bt_kernel<true, true, false><<<dim3(36, 16), 256, 0, stream>>>(
        Abf, Wt, fc6_b + 4608, (void*)(h6bf + 4608), 9216, 4608, 4608);

    // 7: fc7 = h6bf[2048,9216] x fc7_w[9216,4096] (+relu) -> h7bf, two halves
    transpose_cvt_kernel<<<dim3(144, 32), 256, 0, stream>>>(fc7_w, Wt, 9216, 4096, 0);
    gemm_bt_kernel<true, true, false><<<dim3(16, 16), 256, 0, stream>>>(
        h6bf, Wt, fc7_b + 0, (void*)(h7bf + 0), 4096, 9216, 9216);
    transpose_cvt_kernel<<<dim3(144, 32), 256, 0, stream>>>(fc7_w, Wt, 9216, 4096, 2048);
    gemm_bt_kernel<true, true, false><<<dim3(16, 16), 256, 0, stream>>>(
        h6bf, Wt, fc7_b + 2048, (void*)(h7bf + 2048), 4096, 9216, 9216);

    // 8: fc8 both streams, split-K x8: h7bf[2048,4096] x Wt8^T -> P8 -> logits
    pack_w8_kernel<<<dim3(2048), 256, 0, stream>>>(fc8c_w, fc8d_w, Wt8);
    pack_b8_kernel<<<dim3(1), 128, 0, stream>>>(fc8c_b, fc8d_b, b8);
    gemm_bt_kernel<false, false, true><<<dim3(1, 16, 8), 256, 0, stream>>>(
        h7bf, Wt8, b8, (void*)P8, 128, 4096, 512);
    reduce8_kernel<<<dim3(1024), 256, 0, stream>>>(P8, b8, logits);

    // 9: softmaxes + scores + clipped colsum
    colstats_kernel<<<dim3(NCL), 256, 0, stream>>>(logits, cmax, csum);
    scores_kernel<<<dim3(8), 256, 0, stream>>>(logits, cmax, csum, scd, outScores);
    colsum_kernel<<<dim3(NCL), 256, 0, stream>>>(scd, out);
}

// Round 4
// 1284.535 us; speedup vs baseline: 1.4533x; 1.3993x over previous
//
#include <hip/hip_runtime.h>
#include <math.h>

// ---------------------------------------------------------------------------
// WeaklySupervisedDetection
//   Phases 1-4 (conv/obj/topk/boxes): f32-bit-exact chains — DO NOT TOUCH the
//   arithmetic ORDER; they reproduce the np reference's ordering.
//   conv v4: LDS x staging + weight double-buffer prefetch (bit-exact order).
//   GEMM v4: BK=64, [m][k] LDS rows padded to 144B (9 chunks; pad = dup of
//   chunk0, never read) -> staging row-coalesced AND fragment reads 2-way
//   only; A+B contiguous (2304 slots, 9 gl_lds/thread, linear dest);
//   2-phase prefetch with plain __syncthreads (T3-minimum recipe);
//   bijective XCD swizzle. fc8 split-K x8 + deterministic reduce.
//   Softmaxes: fp64 math over fp32 logits (tiny kernels).
// ---------------------------------------------------------------------------

#define HN 50
#define WN 50
#define CN 512
#define AN 9
#define KTOP 2048
#define NCL 20
#define NOBJ 22500  // H*W*A

typedef unsigned short ushort_t;
typedef __attribute__((ext_vector_type(8))) short short8;
typedef __attribute__((ext_vector_type(4))) float floatx4;

__device__ __forceinline__ ushort_t bf16_rne(float f) {
    unsigned int u = __float_as_uint(f);
    unsigned int r = (u + 0x7FFFu + ((u >> 16) & 1u)) >> 16;
    return (ushort_t)r;
}

__device__ __forceinline__ void gl_lds16(const void* g, void* l) {
    __builtin_amdgcn_global_load_lds(
        (const __attribute__((address_space(1))) unsigned int*)g,
        (__attribute__((address_space(3))) unsigned int*)l, 16, 0, 0);
}

// ---------------- conv 2x2 SAME, exact f32 tap chains ----------------------
// v4: 256 threads, each owns co pair (2*tid, 2*tid+1). 4 hw positions/block,
// grid 625. Per c-quad: 16x ds_read_b128 broadcast (x), 16x float2 coalesced
// weights — double-buffered so quad k+1's loads overlap quad k's 128 FMAs.
// Chain per output identical to v1/v2: c ascending, one fmaf per c, taps
// combined ((t0+t1)+t2)+t3 + b, relu.
__launch_bounds__(256)
__global__ void conv_chain_kernel(const float* __restrict__ feat,
                                  const float* __restrict__ rpnw,
                                  const float* __restrict__ rpnb,
                                  float* __restrict__ x32)
{
    __shared__ float xs[16 * 512];  // [slot(4hw x 4tap)][cin(512)] = 32 KB
    const int tid = threadIdx.x;
    const int hwBase = blockIdx.x * 4;
    const int co0 = tid * 2;

    // staging: float4 global -> b128 LDS, zero-pad edges
    for (int t = tid; t < 16 * 128; t += 256) {
        int slot = t >> 7, q = t & 127;
        int hwL = slot >> 2, tap = slot & 3;
        int hw = hwBase + hwL;
        int h = hw / WN, w = hw % WN;
        int hy = h + (tap >> 1), wx = w + (tap & 1);
        float4 v = make_float4(0.f, 0.f, 0.f, 0.f);
        if (hy < HN && wx < WN)
            v = *(const float4*)&feat[(size_t)(hy * WN + wx) * CN + q * 4];
        *(float4*)&xs[slot * 512 + q * 4] = v;
    }
    __syncthreads();

    float accx[4][4];  // [i][tap] for co0
    float accy[4][4];  // [i][tap] for co0+1
#pragma unroll
    for (int i = 0; i < 4; i++)
#pragma unroll
        for (int t = 0; t < 4; t++) { accx[i][t] = 0.f; accy[i][t] = 0.f; }

    const float* wbase = rpnw + co0;

    float2 wA[4][4], wB[4][4];  // [cc][tap]

    auto loadw = [&](float2 (&wd)[4][4], int cqv) {
#pragma unroll
        for (int cc = 0; cc < 4; cc++)
#pragma unroll
            for (int t = 0; t < 4; t++)
                wd[cc][t] = *(const float2*)&wbase[(size_t)(t * CN + cqv + cc) * CN];
    };

    auto dofma = [&](const float2 (&wd)[4][4], int cqv) {
        float4 xv[4][4];
#pragma unroll
        for (int i = 0; i < 4; i++)
#pragma unroll
            for (int t = 0; t < 4; t++)
                xv[i][t] = *(const float4*)&xs[(i * 4 + t) * 512 + cqv];
#pragma unroll
        for (int cc = 0; cc < 4; cc++)
#pragma unroll
            for (int i = 0; i < 4; i++)
#pragma unroll
                for (int t = 0; t < 4; t++) {
                    float xvv = cc == 0 ? xv[i][t].x
                              : cc == 1 ? xv[i][t].y
                              : cc == 2 ? xv[i][t].z : xv[i][t].w;
                    accx[i][t] = fmaf(xvv, wd[cc][t].x, accx[i][t]);
                    accy[i][t] = fmaf(xvv, wd[cc][t].y, accy[i][t]);
                }
    };

    loadw(wA, 0);
    for (int cq = 0; cq < CN - 8; cq += 8) {
        loadw(wB, cq + 4);
        dofma(wA, cq);
        loadw(wA, cq + 8);
        dofma(wB, cq + 4);
    }
    loadw(wB, CN - 4);
    dofma(wA, CN - 8);
    dofma(wB, CN - 4);

    float b0 = rpnb[co0], b1 = rpnb[co0 + 1];
#pragma unroll
    for (int i = 0; i < 4; i++) {
        float v0 = ((accx[i][0] + accx[i][1]) + accx[i][2]) + accx[i][3];
        float v1 = ((accy[i][0] + accy[i][1]) + accy[i][2]) + accy[i][3];
        v0 = v0 + b0; v1 = v1 + b1;
        v0 = v0 > 0.f ? v0 : 0.f;
        v1 = v1 > 0.f ? v1 : 0.f;
        float2 o = make_float2(v0, v1);
        *(float2*)&x32[(size_t)(hwBase + i) * CN + co0] = o;
    }
}

// ---------------- objectness: f32 chain -> f32 sigmoid key ------------------
__launch_bounds__(256)
__global__ void obj_chain_kernel(const float* __restrict__ x32,
                                 const float* __restrict__ clsw,
                                 const float* __restrict__ clsb,
                                 float* __restrict__ key)
{
    int i = blockIdx.x * 256 + threadIdx.x;
    if (i >= NOBJ) return;
    int hw = i / AN, a = i % AN;
    const float* xr = x32 + (size_t)hw * CN;
    float acc = 0.f;
    for (int c = 0; c < CN; c++) acc = fmaf(xr[c], clsw[c * AN + a], acc);
    float l32 = acc + clsb[a];
    float s32 = (float)(1.0 / (1.0 + exp(-(double)l32)));
    key[i] = s32;
}

// ---------------- exact top-K rank count on (f32 key desc, idx asc) --------
__launch_bounds__(256)
__global__ void topk_count_kernel(const float* __restrict__ key, int* __restrict__ cnt)
{
    __shared__ float ch[2048];
    int tid = threadIdx.x;
    int j0 = blockIdx.y * 2048;
    for (int t = tid; t < 2048; t += 256) {
        int jg = j0 + t;
        ch[t] = (jg < NOBJ) ? key[jg] : -1.0f;
    }
    int i = blockIdx.x * 256 + tid;
    float vi = (i < NOBJ) ? key[i] : 2.0f;
    __syncthreads();
    int c = 0;
    for (int t = 0; t < 2048; t++) {
        float vj = ch[t];
        int jg = j0 + t;
        c += (vj > vi || (vj == vi && jg < i)) ? 1 : 0;
    }
    if (i < NOBJ && c) atomicAdd(&cnt[i], c);
}

__launch_bounds__(256)
__global__ void topk_scatter_kernel(const int* __restrict__ cnt, int* __restrict__ sorted)
{
    int i = blockIdx.x * 256 + threadIdx.x;
    if (i < NOBJ) {
        int r = cnt[i];
        if (r < KTOP) sorted[r] = i;
    }
}

// ---------------- box regression (f32 chains) + transform (fp64) -----------
__launch_bounds__(256)
__global__ void boxes_kernel(const int* __restrict__ sorted,
                             const float* __restrict__ x32,
                             const float* __restrict__ regw,
                             const float* __restrict__ regb,
                             double* __restrict__ boxd,
                             float* __restrict__ outBoxes)
{
    int k = blockIdx.x * 256 + threadIdx.x;
    if (k >= KTOP) return;
    int i = sorted[k];
    int hw = i / AN, a = i % AN;
    const float* xr = x32 + (size_t)hw * CN;
    float r0 = 0.f, r1 = 0.f, r2 = 0.f, r3 = 0.f;
    for (int c = 0; c < CN; c++) {
        float xv = xr[c];
        const float* wr = regw + (size_t)c * (4 * AN) + 4 * a;
        r0 = fmaf(xv, wr[0], r0);
        r1 = fmaf(xv, wr[1], r1);
        r2 = fmaf(xv, wr[2], r2);
        r3 = fmaf(xv, wr[3], r3);
    }
    r0 = r0 + regb[4 * a + 0];
    r1 = r1 + regb[4 * a + 1];
    r2 = r2 + regb[4 * a + 2];
    r3 = r3 + regb[4 * a + 3];
    double s0 = 1.0 / (1.0 + exp(-(double)r0));
    double s1 = 1.0 / (1.0 + exp(-(double)r1));
    double s2 = 1.0 / (1.0 + exp(-(double)r2));
    double s3 = 1.0 / (1.0 + exp(-(double)r3));
    double x1 = s0 * (double)(WN - 2);
    double x2 = x1 + 1.0 + s1 * ((double)(WN - 1) - x1);
    double y1 = s2 * (double)(HN - 2);
    double y2 = y1 + 1.0 + s3 * ((double)(HN - 1) - y1);
    boxd[4 * k + 0] = x1; boxd[4 * k + 1] = x2;
    boxd[4 * k + 2] = y1; boxd[4 * k + 3] = y2;
    outBoxes[4 * k + 0] = (float)x1; outBoxes[4 * k + 1] = (float)x2;
    outBoxes[4 * k + 2] = (float)y1; outBoxes[4 * k + 3] = (float)y2;
}

// ---------------- ROI align -> pooled [K, 4608] (bf16) ---------------------
__launch_bounds__(256)
__global__ void roi_kernel(const float* __restrict__ feat,
                           const double* __restrict__ boxd,
                           ushort_t* __restrict__ pooled)
{
    int k = blockIdx.x;
    int tid = threadIdx.x;
    double x1 = boxd[4 * k + 0], x2 = boxd[4 * k + 1];
    double y1 = boxd[4 * k + 2], y2 = boxd[4 * k + 3];
    int ix0[3], ix1[3], iy0[3], iy1[3];
    double fx[3], fy[3];
#pragma unroll
    for (int p = 0; p < 3; p++) {
        double t = ((double)p + 0.5) / 3.0;
        double xsv = x1 + (x2 - x1) * t;
        double x0f = floor(xsv);
        fx[p] = xsv - x0f;
        int xi = (int)x0f;
        xi = xi < 0 ? 0 : (xi > WN - 1 ? WN - 1 : xi);
        ix0[p] = xi;
        ix1[p] = (xi + 1 > WN - 1) ? WN - 1 : xi + 1;
        double ysv = y1 + (y2 - y1) * t;
        double y0f = floor(ysv);
        fy[p] = ysv - y0f;
        int yi = (int)y0f;
        yi = yi < 0 ? 0 : (yi > HN - 1 ? HN - 1 : yi);
        iy0[p] = yi;
        iy1[p] = (yi + 1 > HN - 1) ? HN - 1 : yi + 1;
    }
#pragma unroll
    for (int pp = 0; pp < 9; pp++) {
        int py = pp / 3, px = pp % 3;
        double w00 = (1.0 - fy[py]) * (1.0 - fx[px]);
        double w01 = (1.0 - fy[py]) * fx[px];
        double w10 = fy[py] * (1.0 - fx[px]);
        double w11 = fy[py] * fx[px];
        const float* f00 = feat + (size_t)(iy0[py] * WN + ix0[px]) * CN;
        const float* f01 = feat + (size_t)(iy0[py] * WN + ix1[px]) * CN;
        const float* f10 = feat + (size_t)(iy1[py] * WN + ix0[px]) * CN;
        const float* f11 = feat + (size_t)(iy1[py] * WN + ix1[px]) * CN;
        ushort_t* dst = pooled + ((size_t)k * 9 + pp) * CN;
        for (int c = tid; c < CN; c += 256) {
            double v = w00 * (double)f00[c] + w01 * (double)f01[c]
                     + w10 * (double)f10[c] + w11 * (double)f11[c];
            dst[c] = bf16_rne((float)v);
        }
    }
}

// ---------------- transpose + cvt: W fp32 [K,N] cols [n0,n0+Nsub) ----------
//                  -> Wt bf16 [Nsub][K]
__launch_bounds__(256)
__global__ void transpose_cvt_kernel(const float* __restrict__ W,
                                     ushort_t* __restrict__ Wt,
                                     int K, int N, int n0)
{
    __shared__ float tile[64][65];
    const int tid = threadIdx.x;
    const int k0 = blockIdx.x * 64;
    const int nb = blockIdx.y * 64;
#pragma unroll
    for (int q = 0; q < 4; q++) {
        int r = (tid >> 4) + q * 16;
        int c = (tid & 15) * 4;
        float4 v = *(const float4*)&W[(size_t)(k0 + r) * N + n0 + nb + c];
        tile[r][c + 0] = v.x; tile[r][c + 1] = v.y;
        tile[r][c + 2] = v.z; tile[r][c + 3] = v.w;
    }
    __syncthreads();
#pragma unroll
    for (int q = 0; q < 4; q++) {
        int rn = (tid >> 4) + q * 16;
        int ck = (tid & 15) * 4;
        ushort4 o;
        o.x = bf16_rne(tile[ck + 0][rn]);
        o.y = bf16_rne(tile[ck + 1][rn]);
        o.z = bf16_rne(tile[ck + 2][rn]);
        o.w = bf16_rne(tile[ck + 3][rn]);
        *(ushort4*)&Wt[(size_t)(nb + rn) * K + k0 + ck] = o;
    }
}

// ---------------- pack fc8 weights: [4096,20]x2 -> bf16 [128][4096] --------
__launch_bounds__(256)
__global__ void pack_w8_kernel(const float* __restrict__ cw,
                               const float* __restrict__ dw,
                               ushort_t* __restrict__ Wt8)
{
    int idx = blockIdx.x * 256 + threadIdx.x;  // 128*4096 total
    int n = idx >> 12, k = idx & 4095;
    float v = 0.f;
    if (n < NCL) v = cw[(size_t)k * NCL + n];
    else if (n < 2 * NCL) v = dw[(size_t)k * NCL + (n - NCL)];
    Wt8[(size_t)n * 4096 + k] = bf16_rne(v);
}

__launch_bounds__(128)
__global__ void pack_b8_kernel(const float* __restrict__ cb,
                               const float* __restrict__ db,
                               float* __restrict__ b8)
{
    int n = threadIdx.x;
    float v = 0.f;
    if (n < NCL) v = cb[n];
    else if (n < 2 * NCL) v = db[n - NCL];
    b8[n] = v;
}

// ---------------- bf16 MFMA GEMM v4 ----------------------------------------
// A [M,Krow] bf16 row-major, Bt [Nsub,Krow] bf16 row-major (= B^T), C row
// stride Nc. Tile 128x128, BK=64, 4 waves x (4x4) 16x16x32 tiles x 2 k-steps.
// LDS: one contiguous block of 2304 16B-slots per buffer.
//   A slots [0,1152): slot = m*9 + c; B slots [1152,2304): 1152 + n*9 + c.
//   c in [0,8) = k-chunk (8 bf16); c==8 is a PAD slot (dup of chunk 0,
//   never read) -> row stride 144B: staging stays row-contiguous (good
//   coalescing) and fragment ds_read_b128 is 2-way-only (4-bank row shift).
// Staging: 9 gl_lds/thread, dest linear slot = i*256+tid (rule 21: dest
// wave-uniform base + lane*16; per-lane source free).
// 2-phase prefetch (T3-minimum): stage(next) issued BEFORE compute(cur),
// one __syncthreads (built-in vmcnt drain) per tile.
// SPLITK: grid.z chunks of kLen, f32 partials (no bias), reduce adds bias.
template <bool OUT_BF16, bool RELU, bool SPLITK>
__launch_bounds__(256)
__global__ void gemm_bt_kernel(const ushort_t* __restrict__ A,
                               const ushort_t* __restrict__ Bt,
                               const float* __restrict__ bias,
                               void* __restrict__ Cv,
                               int Nc, int Krow, int kLen)
{
    __shared__ ushort_t ABs[2][2304 * 8];  // 2 x 36 KB
    const int tid = threadIdx.x;
    const int w = tid >> 6, l = tid & 63;

    // bijective XCD swizzle (m204) on column-major linear tile id
    const int nwg = gridDim.x * gridDim.y;
    const int hwid = blockIdx.y * gridDim.x + blockIdx.x;
    const int q = nwg >> 3, r = nwg & 7;
    const int xcd = hwid & 7, i0 = hwid >> 3;
    const int swz = (xcd < r ? xcd * (q + 1) : r * (q + 1) + (xcd - r) * q) + i0;
    const int nBase = (swz / gridDim.y) * 128;
    const int mBase = (swz % gridDim.y) * 128;
    const int mW = (w >> 1) * 64, nW = (w & 1) * 64;

    const int kb0 = SPLITK ? blockIdx.z * kLen : 0;
    const int T = kLen / 64;

    // per-thread staging sources for the 9 slots (slot s = i*256 + tid)
    const ushort_t* srcp[9];
#pragma unroll
    for (int i = 0; i < 9; i++) {
        int s = i * 256 + tid;
        int isB = (s >= 1152) ? 1 : 0;
        int s2 = isB ? s - 1152 : s;
        int row = s2 / 9, c = s2 % 9;
        if (c == 8) c = 0;  // pad slot: harmless dup, never read
        srcp[i] = (isB ? Bt + (size_t)(nBase + row) * Krow
                       : A + (size_t)(mBase + row) * Krow) + kb0 + c * 8;
    }

    auto stage = [&](int buf, int kb) {
#pragma unroll
        for (int i = 0; i < 9; i++)
            gl_lds16(srcp[i] + kb, &ABs[buf][(i * 256 + tid) * 8]);
    };

    floatx4 acc[4][4];
#pragma unroll
    for (int i = 0; i < 4; i++)
#pragma unroll
        for (int j = 0; j < 4; j++) acc[i][j] = (floatx4){0.f, 0.f, 0.f, 0.f};

    stage(0, 0);
    __syncthreads();

    int buf = 0;
    for (int it = 0; it < T; ++it) {
        if (it + 1 < T) stage(buf ^ 1, (it + 1) * 64);
#pragma unroll
        for (int u = 0; u < 2; u++) {
            short8 aF[4], bF[4];
#pragma unroll
            for (int i = 0; i < 4; i++)
                aF[i] = *(const short8*)&ABs[buf][
                    ((mW + i * 16 + (l & 15)) * 9 + u * 4 + (l >> 4)) * 8];
#pragma unroll
            for (int j = 0; j < 4; j++)
                bF[j] = *(const short8*)&ABs[buf][
                    (1152 + (nW + j * 16 + (l & 15)) * 9 + u * 4 + (l >> 4)) * 8];
#pragma unroll
            for (int i = 0; i < 4; i++)
#pragma unroll
                for (int j = 0; j < 4; j++)
                    acc[i][j] = __builtin_amdgcn_mfma_f32_16x16x32_bf16(
                        aF[i], bF[j], acc[i][j], 0, 0, 0);
        }
        __syncthreads();
        buf ^= 1;
    }

    float* Cp = (float*)Cv;
    if (SPLITK) Cp += (size_t)blockIdx.z * (size_t)gridDim.y * 128 * Nc;

#pragma unroll
    for (int i = 0; i < 4; i++) {
        int rowT = mBase + mW + i * 16 + (l >> 4) * 4;
#pragma unroll
        for (int j = 0; j < 4; j++) {
            int col = nBase + nW + j * 16 + (l & 15);
            float bv = SPLITK ? 0.f : bias[col];
#pragma unroll
            for (int r2 = 0; r2 < 4; r2++) {
                float v = acc[i][j][r2] + bv;
                if (RELU) v = v > 0.f ? v : 0.f;
                size_t idx = (size_t)(rowT + r2) * Nc + col;
                if (OUT_BF16) ((ushort_t*)Cv)[idx] = bf16_rne(v);
                else Cp[idx] = v;
            }
        }
    }
}

// ---------------- fc8 split-K reduce: logits = sum_s P[s] + bias -----------
__launch_bounds__(256)
__global__ void reduce8_kernel(const float* __restrict__ P,
                               const float* __restrict__ b8,
                               float* __restrict__ logits)
{
    int idx = blockIdx.x * 256 + threadIdx.x;  // 2048*128 total
    int j = idx & 127;
    float s = 0.f;
#pragma unroll
    for (int c = 0; c < 8; c++) s += P[(size_t)c * KTOP * 128 + idx];
    logits[idx] = s + b8[j];
}

// ---------------- softmax column stats over fp32 logits --------------------
// logits layout: [KTOP][128]; cols 0..19 = c-stream, 20..39 = d-stream
__launch_bounds__(256)
__global__ void colstats_kernel(const float* __restrict__ logits,
                                double* __restrict__ cmax, double* __restrict__ csum)
{
    __shared__ double red[4];
    int j = blockIdx.x, tid = threadIdx.x;
    double m = -1.0e300;
    for (int i = tid; i < KTOP; i += 256) m = fmax(m, (double)logits[(size_t)i * 128 + j]);
    for (int off = 32; off > 0; off >>= 1) m = fmax(m, __shfl_down(m, off, 64));
    if ((tid & 63) == 0) red[tid >> 6] = m;
    __syncthreads();
    double mm = fmax(fmax(red[0], red[1]), fmax(red[2], red[3]));
    __syncthreads();
    double s = 0.0;
    for (int i = tid; i < KTOP; i += 256) s += exp((double)logits[(size_t)i * 128 + j] - mm);
    for (int off = 32; off > 0; off >>= 1) s += __shfl_down(s, off, 64);
    if ((tid & 63) == 0) red[tid >> 6] = s;
    __syncthreads();
    if (tid == 0) { cmax[j] = mm; csum[j] = red[0] + red[1] + red[2] + red[3]; }
}

// ---------------- row softmax + scores ---------------------------------------
__launch_bounds__(256)
__global__ void scores_kernel(const float* __restrict__ logits,
                              const double* __restrict__ cmax, const double* __restrict__ csum,
                              double* __restrict__ scd, float* __restrict__ outScores)
{
    int i = blockIdx.x * 256 + threadIdx.x;
    if (i >= KTOP) return;
    const float* lr = logits + (size_t)i * 128;
    double rm = -1.0e300;
#pragma unroll
    for (int j = 0; j < NCL; j++) rm = fmax(rm, (double)lr[NCL + j]);
    double rs = 0.0;
#pragma unroll
    for (int j = 0; j < NCL; j++) rs += exp((double)lr[NCL + j] - rm);
#pragma unroll
    for (int j = 0; j < NCL; j++) {
        double cc = exp((double)lr[j] - cmax[j]) / csum[j];
        double dd = exp((double)lr[NCL + j] - rm) / rs;
        double sc = cc * dd;
        scd[(size_t)i * NCL + j] = sc;
        outScores[(size_t)i * NCL + j] = (float)sc;
    }
}

// ---------------- column sum + clip -----------------------------------------
__launch_bounds__(256)
__global__ void colsum_kernel(const double* __restrict__ scd, float* __restrict__ out)
{
    __shared__ double red[4];
    int j = blockIdx.x, tid = threadIdx.x;
    double s = 0.0;
    for (int i = tid; i < KTOP; i += 256) s += scd[(size_t)i * NCL + j];
    for (int off = 32; off > 0; off >>= 1) s += __shfl_down(s, off, 64);
    if ((tid & 63) == 0) red[tid >> 6] = s;
    __syncthreads();
    if (tid == 0) {
        double t = red[0] + red[1] + red[2] + red[3];
        t = t < 0.0 ? 0.0 : (t > 1.0 ? 1.0 : t);
        out[j] = (float)t;
    }
}

// ---------------------------------------------------------------------------
extern "C" void kernel_launch(void* const* d_in, const int* in_sizes, int n_in,
                              void* d_out, int out_size, void* d_ws, size_t ws_size,
                              hipStream_t stream)
{
    const float* features = (const float*)d_in[0];
    const float* rpn_w  = (const float*)d_in[2];
    const float* rpn_b  = (const float*)d_in[3];
    const float* cls_w  = (const float*)d_in[4];
    const float* cls_b  = (const float*)d_in[5];
    const float* reg_w  = (const float*)d_in[6];
    const float* reg_b  = (const float*)d_in[7];
    const float* fc6_w  = (const float*)d_in[8];
    const float* fc6_b  = (const float*)d_in[9];
    const float* fc7_w  = (const float*)d_in[10];
    const float* fc7_b  = (const float*)d_in[11];
    const float* fc8c_w = (const float*)d_in[12];
    const float* fc8c_b = (const float*)d_in[13];
    const float* fc8d_w = (const float*)d_in[14];
    const float* fc8d_b = (const float*)d_in[15];

    float* out = (float*)d_out;
    char* ws = (char*)d_ws;

    // ---- workspace layout (phase-overlapped; peak ~99 MB) ----
    const size_t OFF_H6   = 0;
    const size_t OFF_WT   = 37748736;
    const size_t OFF_ABF  = 80216064;
    const size_t OFF_H7   = 80216064;
    // early smalls (inside h6bf region):
    const size_t OFF_X32  = 0;
    const size_t OFF_KEY  = 5120000;
    const size_t OFF_CNT  = 5210112;
    const size_t OFF_SORT = 5300224;
    const size_t OFF_BOXD = 5308416;
    // fc8 split-K partials: Wt region is dead after fc7 gemms (8 MB used)
    const size_t OFF_P8   = OFF_WT;
    // late smalls (WtBuf tail, free during/after GEMM2):
    const size_t OFF_LOGIT = OFF_WT + 37748736;          // 2048*128*4 = 1,048,576
    const size_t OFF_W8T   = OFF_LOGIT + 1048576;        // 128*4096*2 = 1,048,576
    const size_t OFF_B8    = OFF_W8T + 1048576;          // 512
    const size_t OFF_SCD   = OFF_B8 + 512;               // 327,680
    const size_t OFF_CMAX  = OFF_SCD + 327680;           // 512
    const size_t OFF_CSUM  = OFF_CMAX + 512;             // 512

    float*    x32    = (float*)(ws + OFF_X32);
    float*    key    = (float*)(ws + OFF_KEY);
    int*      cnt    = (int*)(ws + OFF_CNT);
    int*      sorted = (int*)(ws + OFF_SORT);
    double*   boxd   = (double*)(ws + OFF_BOXD);
    ushort_t* Abf    = (ushort_t*)(ws + OFF_ABF);
    ushort_t* Wt     = (ushort_t*)(ws + OFF_WT);
    ushort_t* h6bf   = (ushort_t*)(ws + OFF_H6);
    ushort_t* h7bf   = (ushort_t*)(ws + OFF_H7);
    float*    P8     = (float*)(ws + OFF_P8);
    float*    logits = (float*)(ws + OFF_LOGIT);
    ushort_t* Wt8    = (ushort_t*)(ws + OFF_W8T);
    float*    b8     = (float*)(ws + OFF_B8);
    double*   scd    = (double*)(ws + OFF_SCD);
    double*   cmax   = (double*)(ws + OFF_CMAX);
    double*   csum   = (double*)(ws + OFF_CSUM);

    float* outScores = out + NCL;
    float* outBoxes  = out + NCL + KTOP * NCL;

    // 1-4: bit-exact RPN path (conv v4: v2 structure + weight dbuf prefetch)
    conv_chain_kernel<<<dim3(625), 256, 0, stream>>>(features, rpn_w, rpn_b, x32);
    obj_chain_kernel<<<dim3(88), 256, 0, stream>>>(x32, cls_w, cls_b, key);
    hipMemsetAsync(cnt, 0, NOBJ * sizeof(int), stream);
    topk_count_kernel<<<dim3(88, 11), 256, 0, stream>>>(key, cnt);
    topk_scatter_kernel<<<dim3(88), 256, 0, stream>>>(cnt, sorted);
    boxes_kernel<<<dim3(8), 256, 0, stream>>>(sorted, x32, reg_w, reg_b, boxd, outBoxes);

    // 5: ROI align -> Abf (bf16)
    roi_kernel<<<dim3(KTOP), 256, 0, stream>>>(features, boxd, Abf);

    // 6: fc6 = Abf[2048,4608] x fc6_w[4608,9216] (+relu) -> h6bf, two N-halves
    transpose_cvt_kernel<<<dim3(72, 72), 256, 0, stream>>>(fc6_w, Wt, 4608, 9216, 0);
    gemm_bt_kernel<true, true, false><<<dim3(36, 16), 256, 0, stream>>>(
        Abf, Wt, fc6_b + 0, (void*)(h6bf + 0), 9216, 4608, 4608);
    transpose_cvt_kernel<<<dim3(72, 72), 256, 0, stream>>>(fc6_w, Wt, 4608, 9216, 4608);
    gemm_bt_kernel<true, true, false><<<dim3(36, 16), 256, 0, stream>>>(
        Abf, Wt, fc6_b + 4608, (void*)(h6bf + 4608), 9216, 4608, 4608);

    // 7: fc7 = h6bf[2048,9216] x fc7_w[9216,4096] (+relu) -> h7bf, two halves
    transpose_cvt_kernel<<<dim3(144, 32), 256, 0, stream>>>(fc7_w, Wt, 9216, 4096, 0);
    gemm_bt_kernel<true, true, false><<<dim3(16, 16), 256, 0, stream>>>(
        h6bf, Wt, fc7_b + 0, (void*)(h7bf + 0), 4096, 9216, 9216);
    transpose_cvt_kernel<<<dim3(144, 32), 256, 0, stream>>>(fc7_w, Wt, 9216, 4096, 2048);
    gemm_bt_kernel<true, true, false><<<dim3(16, 16), 256, 0, stream>>>(
        h6bf, Wt, fc7_b + 2048, (void*)(h7bf + 2048), 4096, 9216, 9216);

    // 8: fc8 both streams, split-K x8: h7bf[2048,4096] x Wt8^T -> P8 -> logits
    pack_w8_kernel<<<dim3(2048), 256, 0, stream>>>(fc8c_w, fc8d_w, Wt8);
    pack_b8_kernel<<<dim3(1), 128, 0, stream>>>(fc8c_b, fc8d_b, b8);
    gemm_bt_kernel<false, false, true><<<dim3(1, 16, 8), 256, 0, stream>>>(
        h7bf, Wt8, b8, (void*)P8, 128, 4096, 512);
    reduce8_kernel<<<dim3(1024), 256, 0, stream>>>(P8, b8, logits);

    // 9: softmaxes + scores + clipped colsum
    colstats_kernel<<<dim3(NCL), 256, 0, stream>>>(logits, cmax, csum);
    scores_kernel<<<dim3(8), 256, 0, stream>>>(logits, cmax, csum, scd, outScores);
    colsum_kernel<<<dim3(NCL), 256, 0, stream>>>(scd, out);
}